// Round 3
// baseline (30668.674 us; speedup 1.0000x reference)
//
#include <hip/hip_runtime.h>
#include <hip/hip_bf16.h>
#include <stdint.h>

#define TT 2048
#define DD 2048
#define HDIM 1024
#define G4 4096
#define KTAG 22
#define END_TAG 20
#define START_TAG 21
#define NEGV (-10000.0f)

typedef __attribute__((ext_vector_type(8))) short bf16x8;
typedef __attribute__((ext_vector_type(4))) float f32x4;

__device__ __forceinline__ float sigm(float x) { return 1.0f / (1.0f + __expf(-x)); }
__device__ __forceinline__ float tanh_fast(float x) {
    float e = __expf(2.0f * x);
    return 1.0f - 2.0f / (e + 1.0f);
}

// ---------------- prep: fp32 -> bf16 ----------------
__global__ void convert_bf16_k(const float* __restrict__ src, __hip_bfloat16* __restrict__ dst, int n) {
    int i = blockIdx.x * blockDim.x + threadIdx.x;
    int stride = gridDim.x * blockDim.x;
    for (; i < n; i += stride) dst[i] = __float2bfloat16(src[i]);
}

__global__ void make_bias_k(const float* __restrict__ bih_f, const float* __restrict__ bhh_f,
                            const float* __restrict__ bih_r, const float* __restrict__ bhh_r,
                            float* __restrict__ ball) {
    int j = blockIdx.x * 256 + threadIdx.x;
    if (j < G4) ball[j] = bih_f[j] + bhh_f[j];
    else if (j < 2 * G4) ball[j] = bih_r[j - G4] + bhh_r[j - G4];
}

// ---------------- GEMM: X[t][j] = sum_k seq[t][k]*W[j][k] + bias[j] ----------------
#define LDT 40
__global__ __launch_bounds__(256) void gemm_x_k(const __hip_bfloat16* __restrict__ A,
                                                const __hip_bfloat16* __restrict__ B,
                                                const float* __restrict__ bias,
                                                float* __restrict__ X) {
    __shared__ unsigned short As[128 * LDT];
    __shared__ unsigned short Bs[128 * LDT];
    const int tid  = threadIdx.x;
    const int lane = tid & 63;
    const int wave = tid >> 6;
    const int wm = wave >> 1, wn = wave & 1;
    const int m0 = blockIdx.y * 128, n0 = blockIdx.x * 128;
    const int r15 = lane & 15, quad = lane >> 4;

    f32x4 acc[4][4];
#pragma unroll
    for (int i = 0; i < 4; ++i)
#pragma unroll
        for (int j = 0; j < 4; ++j) acc[i][j] = (f32x4){0.f, 0.f, 0.f, 0.f};

    for (int kt = 0; kt < DD; kt += 32) {
#pragma unroll
        for (int it = 0; it < 2; ++it) {
            int idx = it * 256 + tid;
            int row = idx >> 2, ch = idx & 3;
            uint4 va = *(const uint4*)(A + (size_t)(m0 + row) * DD + kt + ch * 8);
            *(uint4*)(&As[row * LDT + ch * 8]) = va;
            uint4 vb = *(const uint4*)(B + (size_t)(n0 + row) * DD + kt + ch * 8);
            *(uint4*)(&Bs[row * LDT + ch * 8]) = vb;
        }
        __syncthreads();
        bf16x8 af[4], bfr[4];
#pragma unroll
        for (int i = 0; i < 4; ++i)
            af[i] = *(const bf16x8*)(&As[(wm * 64 + i * 16 + r15) * LDT + quad * 8]);
#pragma unroll
        for (int j = 0; j < 4; ++j)
            bfr[j] = *(const bf16x8*)(&Bs[(wn * 64 + j * 16 + r15) * LDT + quad * 8]);
#pragma unroll
        for (int i = 0; i < 4; ++i)
#pragma unroll
            for (int j = 0; j < 4; ++j)
                acc[i][j] = __builtin_amdgcn_mfma_f32_16x16x32_bf16(af[i], bfr[j], acc[i][j], 0, 0, 0);
        __syncthreads();
    }
#pragma unroll
    for (int i = 0; i < 4; ++i) {
#pragma unroll
        for (int j = 0; j < 4; ++j) {
            int col = n0 + wn * 64 + j * 16 + r15;
            float b = bias[col];
#pragma unroll
            for (int r = 0; r < 4; ++r) {
                int row = m0 + wm * 64 + i * 16 + quad * 4 + r;
                X[(size_t)row * (2 * G4) + col] = acc[i][j][r] + b;
            }
        }
    }
}

// ---------------- persistent bidirectional LSTM recurrence ----------------
// grid = 128 WGs: dir = bid&1, slice = bid>>1. 512 threads (8 waves).
// Lane owns Whh[row][coff..coff+128) in VGPRs; wave w depends only on producer
// slices [w*8, w*8+8) for its h chunk -> per-wave relaxed poll + one acquire
// fence; one __syncthreads per step (cross-wave partial reduce, part[] double-
// buffered by t&1).
__global__ __launch_bounds__(512, 2) void lstm_recur_k(
    const float* __restrict__ Whh_f, const float* __restrict__ Whh_r,
    const float* __restrict__ h0, const float* __restrict__ c0,
    const float* __restrict__ X,   // [2048][8192]
    float* h_buf,                  // [2 dir][2 buf][1024]
    int* flags,                    // [2 dir][64]
    float* __restrict__ hs_out)    // [2048][2048]
{
    const int bid = blockIdx.x;
    const int dir = bid & 1;
    const int slice = bid >> 1;
    const int tid = threadIdx.x;
    const int lane = tid & 63;
    const int wave = tid >> 6;

    __shared__ float h_ch[8][128];     // per-wave private h chunk
    __shared__ float part[2][8][64];   // [t&1][wave][row]

    const float* Whh = dir ? Whh_r : Whh_f;
    float* hb = h_buf + dir * 2048;
    int* fl = flags + dir * 64;

    const int gate = lane >> 4, kk = lane & 15;
    const int row = gate * HDIM + slice * 16 + kk;  // 0..4095
    const int coff = wave * 128;
    const int base8 = wave * 8;

    // weights -> registers (one-time)
    float w[128];
    {
        const float4* wp = (const float4*)(Whh + (size_t)row * HDIM + coff);
#pragma unroll
        for (int i = 0; i < 32; ++i) {
            float4 v = wp[i];
            w[4 * i + 0] = v.x; w[4 * i + 1] = v.y; w[4 * i + 2] = v.z; w[4 * i + 3] = v.w;
        }
    }

    float c_reg = 0.f;
    if (wave == 0) {
        if (lane < 16) {
            __hip_atomic_store(&hb[slice * 16 + lane], h0[dir * HDIM + slice * 16 + lane],
                               __ATOMIC_RELAXED, __HIP_MEMORY_SCOPE_AGENT);
            c_reg = c0[dir * HDIM + slice * 16 + lane];
        }
        if (lane == 0) __hip_atomic_store(&fl[slice], 0, __ATOMIC_RELEASE, __HIP_MEMORY_SCOPE_AGENT);
    }

    for (int t = 0; t < TT; ++t) {
        // relaxed poll of this wave's 8 producer slices (8-way lane replication)
        while (__any(__hip_atomic_load(&fl[base8 + (lane & 7)], __ATOMIC_RELAXED,
                                       __HIP_MEMORY_SCOPE_AGENT) < t)) {
            __builtin_amdgcn_s_sleep(1);
        }
        __builtin_amdgcn_fence(__ATOMIC_ACQUIRE, "agent");

        const int tx = dir ? (TT - 1 - t) : t;
        float xv = 0.f;
        if (wave == 0) xv = X[(size_t)tx * (2 * G4) + dir * G4 + row];  // overlaps h stage + GEMV

        // stage this wave's 128-float h chunk into private LDS: 64 lanes x 8B.
        // (no barrier: same-wave DS ops execute in issue order)
        {
            const unsigned long long* hsrc =
                (const unsigned long long*)(hb + (t & 1) * 1024 + coff);
            unsigned long long hv = __hip_atomic_load(hsrc + lane, __ATOMIC_RELAXED,
                                                      __HIP_MEMORY_SCOPE_AGENT);
            *(unsigned long long*)(&h_ch[wave][lane * 2]) = hv;
        }
        // partial GEMV: this lane's row over its 128-col chunk (LDS broadcast reads)
        float a0 = 0.f, a1 = 0.f;
        const float4* h4 = (const float4*)h_ch[wave];
#pragma unroll
        for (int i = 0; i < 32; i += 2) {
            float4 x = h4[i], y = h4[i + 1];
            a0 = fmaf(w[4 * i + 0], x.x, a0); a0 = fmaf(w[4 * i + 1], x.y, a0);
            a0 = fmaf(w[4 * i + 2], x.z, a0); a0 = fmaf(w[4 * i + 3], x.w, a0);
            a1 = fmaf(w[4 * i + 4], y.x, a1); a1 = fmaf(w[4 * i + 5], y.y, a1);
            a1 = fmaf(w[4 * i + 6], y.z, a1); a1 = fmaf(w[4 * i + 7], y.w, a1);
        }
        part[t & 1][wave][lane] = a0 + a1;
        __syncthreads();   // the single per-step barrier

        if (wave == 0) {
            float g = xv;
#pragma unroll
            for (int wv = 0; wv < 8; ++wv) g += part[t & 1][wv][lane];
            // gather the 4 gate pre-activations for hidden unit kk into lanes 0..15
            float g1 = __shfl(g, kk + 16);
            float g2 = __shfl(g, kk + 32);
            float g3 = __shfl(g, kk + 48);
            if (lane < 16) {
                float iv = sigm(g);
                float fv = sigm(g1);
                float gg = tanh_fast(g2);
                float ov = sigm(g3);
                float c = fv * c_reg + iv * gg;
                c_reg = c;
                float h = ov * tanh_fast(c);
                hs_out[(size_t)tx * 2048 + dir * HDIM + slice * 16 + lane] = h;
                __hip_atomic_store(&hb[((t + 1) & 1) * 1024 + slice * 16 + lane], h,
                                   __ATOMIC_RELAXED, __HIP_MEMORY_SCOPE_AGENT);
            }
            if (lane == 0)
                __hip_atomic_store(&fl[slice], t + 1, __ATOMIC_RELEASE, __HIP_MEMORY_SCOPE_AGENT);
        }
    }
}

// ---------------- feats = lstm_out @ W_tag^T + b_tag ----------------
__global__ __launch_bounds__(256) void feats_k(const float* __restrict__ hs,
                                               const float* __restrict__ Wtag,
                                               const float* __restrict__ btag,
                                               float* __restrict__ feats) {
    const int t = blockIdx.x;
    const int lane = threadIdx.x & 63, wave = threadIdx.x >> 6;
    const float* ht = hs + (size_t)t * 2048;
    for (int j = wave; j < KTAG; j += 4) {
        const float* wr = Wtag + (size_t)j * 2048;
        float acc = 0.f;
#pragma unroll
        for (int i = 0; i < 32; ++i) acc += wr[i * 64 + lane] * ht[i * 64 + lane];
#pragma unroll
        for (int off = 32; off; off >>= 1) acc += __shfl_xor(acc, off);
        if (lane == 0) feats[t * KTAG + j] = acc + btag[j];
    }
}

// ---------------- Viterbi (single wave) ----------------
__global__ __launch_bounds__(64) void viterbi_k(const float* __restrict__ feats,
                                                const float* __restrict__ trans,
                                                float* __restrict__ out) {
    __shared__ float fv[KTAG];
    __shared__ unsigned char bps[TT * KTAG];
    __shared__ short path[TT];
    __shared__ float term[KTAG];
    const int j = threadIdx.x;
    float tr[KTAG];
    float tEnd = 0.f;
    if (j < KTAG) {
#pragma unroll
        for (int p = 0; p < KTAG; ++p) tr[p] = trans[j * KTAG + p];
        tEnd = trans[END_TAG * KTAG + j];
        fv[j] = (j == START_TAG) ? 0.0f : NEGV;
    }
    __syncthreads();
    for (int t = 0; t < TT; ++t) {
        float m = -3.4e38f;
        int bp = 0;
        float ft = 0.f;
        if (j < KTAG) {
            ft = feats[t * KTAG + j];
#pragma unroll
            for (int p = 0; p < KTAG; ++p) {
                float v = tr[p] + fv[p];
                if (v > m) { m = v; bp = p; }
            }
        }
        __syncthreads();
        if (j < KTAG) {
            fv[j] = m + ft;
            bps[t * KTAG + j] = (unsigned char)bp;
        }
        __syncthreads();
    }
    if (j < KTAG) term[j] = fv[j] + tEnd;
    __syncthreads();
    if (j == 0) {
        float best = term[0];
        int bt = 0;
        for (int p = 1; p < KTAG; ++p)
            if (term[p] > best) { best = term[p]; bt = p; }
        out[0] = best;
        int tag = bt;
        for (int t = TT - 1; t >= 0; --t) {
            path[t] = (short)tag;
            tag = bps[t * KTAG + tag];
        }
    }
    __syncthreads();
    for (int t = threadIdx.x; t < TT; t += 64) out[1 + t] = (float)path[t];
}

// ---------------- host ----------------
extern "C" void kernel_launch(void* const* d_in, const int* in_sizes, int n_in,
                              void* d_out, int out_size, void* d_ws, size_t ws_size,
                              hipStream_t stream) {
    const float* seq   = (const float*)d_in[0];
    const float* h0    = (const float*)d_in[1];
    const float* c0    = (const float*)d_in[2];
    const float* Wih_f = (const float*)d_in[3];
    const float* Whh_f = (const float*)d_in[4];
    const float* bih_f = (const float*)d_in[5];
    const float* bhh_f = (const float*)d_in[6];
    const float* Wih_r = (const float*)d_in[7];
    const float* Whh_r = (const float*)d_in[8];
    const float* bih_r = (const float*)d_in[9];
    const float* bhh_r = (const float*)d_in[10];
    const float* Wtag  = (const float*)d_in[11];
    const float* btag  = (const float*)d_in[12];
    const float* trans = (const float*)d_in[13];

    char* ws = (char*)d_ws;
    const size_t MB = 1ull << 20;
    __hip_bfloat16* seq_bf = (__hip_bfloat16*)(ws);              // 8 MB
    __hip_bfloat16* w_bf   = (__hip_bfloat16*)(ws + 8 * MB);     // 32 MB
    float* bias  = (float*)(ws + 40 * MB);                       // 32 KB
    float* X     = (float*)(ws + 41 * MB);                       // 64 MB
    float* hs    = (float*)(ws + 105 * MB);                      // 16 MB
    float* feats = (float*)(ws + 121 * MB);                      // 192 KB
    float* h_buf = (float*)(ws + 122 * MB);                      // 16 KB
    int*   flags = (int*)(ws + 122 * MB + 16384);                // 512 B

    hipMemsetAsync(flags, 0xFF, 2 * 64 * sizeof(int), stream);
    convert_bf16_k<<<256, 256, 0, stream>>>(seq, seq_bf, DD * TT);
    convert_bf16_k<<<512, 256, 0, stream>>>(Wih_f, w_bf, G4 * DD);
    convert_bf16_k<<<512, 256, 0, stream>>>(Wih_r, w_bf + (size_t)G4 * DD, G4 * DD);
    make_bias_k<<<32, 256, 0, stream>>>(bih_f, bhh_f, bih_r, bhh_r, bias);
    gemm_x_k<<<dim3(64, 16), 256, 0, stream>>>(seq_bf, w_bf, bias, X);

    {
        const float* a0 = Whh_f; const float* a1 = Whh_r;
        const float* a2 = h0;    const float* a3 = c0;
        const float* a4 = X;     float* a5 = h_buf;
        int* a6 = flags;         float* a7 = hs;
        void* args[] = {&a0, &a1, &a2, &a3, &a4, &a5, &a6, &a7};
        hipLaunchCooperativeKernel((const void*)lstm_recur_k, dim3(128), dim3(512), args, 0, stream);
    }

    feats_k<<<TT, 256, 0, stream>>>(hs, Wtag, btag, feats);
    viterbi_k<<<1, 64, 0, stream>>>(feats, trans, (float*)d_out);
}

// Round 4
// 6115.683 us; speedup vs baseline: 5.0148x; 5.0148x over previous
//
#include <hip/hip_runtime.h>
#include <hip/hip_bf16.h>
#include <stdint.h>

#define TT 2048
#define DD 2048
#define HDIM 1024
#define G4 4096
#define KTAG 22
#define END_TAG 20
#define START_TAG 21
#define NEGV (-10000.0f)

typedef __attribute__((ext_vector_type(8))) short bf16x8;
typedef __attribute__((ext_vector_type(4))) float f32x4;

__device__ __forceinline__ float sigm(float x) { return 1.0f / (1.0f + __expf(-x)); }
__device__ __forceinline__ float tanh_fast(float x) {
    float e = __expf(2.0f * x);
    return 1.0f - 2.0f / (e + 1.0f);
}

// ---------------- prep: fp32 -> bf16 ----------------
__global__ void convert_bf16_k(const float* __restrict__ src, __hip_bfloat16* __restrict__ dst, int n) {
    int i = blockIdx.x * blockDim.x + threadIdx.x;
    int stride = gridDim.x * blockDim.x;
    for (; i < n; i += stride) dst[i] = __float2bfloat16(src[i]);
}

__global__ void make_bias_k(const float* __restrict__ bih_f, const float* __restrict__ bhh_f,
                            const float* __restrict__ bih_r, const float* __restrict__ bhh_r,
                            float* __restrict__ ball) {
    int j = blockIdx.x * 256 + threadIdx.x;
    if (j < G4) ball[j] = bih_f[j] + bhh_f[j];
    else if (j < 2 * G4) ball[j] = bih_r[j - G4] + bhh_r[j - G4];
}

// ---------------- GEMM: X[t][j] = sum_k seq[t][k]*W[j][k] + bias[j] ----------------
#define LDT 40
__global__ __launch_bounds__(256) void gemm_x_k(const __hip_bfloat16* __restrict__ A,
                                                const __hip_bfloat16* __restrict__ B,
                                                const float* __restrict__ bias,
                                                float* __restrict__ X) {
    __shared__ unsigned short As[128 * LDT];
    __shared__ unsigned short Bs[128 * LDT];
    const int tid  = threadIdx.x;
    const int lane = tid & 63;
    const int wave = tid >> 6;
    const int wm = wave >> 1, wn = wave & 1;
    const int m0 = blockIdx.y * 128, n0 = blockIdx.x * 128;
    const int r15 = lane & 15, quad = lane >> 4;

    f32x4 acc[4][4];
#pragma unroll
    for (int i = 0; i < 4; ++i)
#pragma unroll
        for (int j = 0; j < 4; ++j) acc[i][j] = (f32x4){0.f, 0.f, 0.f, 0.f};

    for (int kt = 0; kt < DD; kt += 32) {
#pragma unroll
        for (int it = 0; it < 2; ++it) {
            int idx = it * 256 + tid;
            int row = idx >> 2, ch = idx & 3;
            uint4 va = *(const uint4*)(A + (size_t)(m0 + row) * DD + kt + ch * 8);
            *(uint4*)(&As[row * LDT + ch * 8]) = va;
            uint4 vb = *(const uint4*)(B + (size_t)(n0 + row) * DD + kt + ch * 8);
            *(uint4*)(&Bs[row * LDT + ch * 8]) = vb;
        }
        __syncthreads();
        bf16x8 af[4], bfr[4];
#pragma unroll
        for (int i = 0; i < 4; ++i)
            af[i] = *(const bf16x8*)(&As[(wm * 64 + i * 16 + r15) * LDT + quad * 8]);
#pragma unroll
        for (int j = 0; j < 4; ++j)
            bfr[j] = *(const bf16x8*)(&Bs[(wn * 64 + j * 16 + r15) * LDT + quad * 8]);
#pragma unroll
        for (int i = 0; i < 4; ++i)
#pragma unroll
            for (int j = 0; j < 4; ++j)
                acc[i][j] = __builtin_amdgcn_mfma_f32_16x16x32_bf16(af[i], bfr[j], acc[i][j], 0, 0, 0);
        __syncthreads();
    }
#pragma unroll
    for (int i = 0; i < 4; ++i) {
#pragma unroll
        for (int j = 0; j < 4; ++j) {
            int col = n0 + wn * 64 + j * 16 + r15;
            float b = bias[col];
#pragma unroll
            for (int r = 0; r < 4; ++r) {
                int row = m0 + wm * 64 + i * 16 + quad * 4 + r;
                X[(size_t)row * (2 * G4) + col] = acc[i][j][r] + b;
            }
        }
    }
}

// ---------------- persistent bidirectional LSTM recurrence ----------------
// grid = 128 WGs: dir = bid&1, slice = bid>>1. 512 threads (8 waves).
// h is published as packed (tag << 32 | fp32 bits) 8B atoms: data IS the flag.
// No fences, no release/acquire, no separate flag array -> one IC round trip
// per step. Double-buffered by t&1; tag t+2 can only be written after every
// WG consumed tag t (global tag order), so no overwrite race.
__global__ __launch_bounds__(512, 2) void lstm_recur_k(
    const float* __restrict__ Whh_f, const float* __restrict__ Whh_r,
    const float* __restrict__ h0, const float* __restrict__ c0,
    const float* __restrict__ X,       // [2048][8192]
    unsigned long long* pairs,         // [2 dir][2 buf][1024]
    float* __restrict__ hs_out)        // [2048][2048]
{
    const int bid = blockIdx.x;
    const int dir = bid & 1;
    const int slice = bid >> 1;
    const int tid = threadIdx.x;
    const int lane = tid & 63;
    const int wave = tid >> 6;

    __shared__ float h_lds[1024];
    __shared__ float part[8][64];

    const float* Whh = dir ? Whh_r : Whh_f;
    unsigned long long* pd = pairs + (size_t)dir * 2048;

    const int gate = lane >> 4, kk = lane & 15;
    const int row = gate * HDIM + slice * 16 + kk;  // 0..4095
    const int coff = wave * 128;

    // weights -> registers (one-time)
    float w[128];
    {
        const float4* wp = (const float4*)(Whh + (size_t)row * HDIM + coff);
#pragma unroll
        for (int i = 0; i < 32; ++i) {
            float4 v = wp[i];
            w[4 * i + 0] = v.x; w[4 * i + 1] = v.y; w[4 * i + 2] = v.z; w[4 * i + 3] = v.w;
        }
    }

    float c_reg = 0.f;
    if (wave == 0 && lane < 16) {
        float hv = h0[dir * HDIM + slice * 16 + lane];
        c_reg = c0[dir * HDIM + slice * 16 + lane];
        // tag 0 in hi word
        unsigned long long pk = (unsigned long long)__float_as_uint(hv);
        __hip_atomic_store(&pd[slice * 16 + lane], pk, __ATOMIC_RELAXED, __HIP_MEMORY_SCOPE_AGENT);
    }

    for (int t = 0; t < TT; ++t) {
        const int tx = dir ? (TT - 1 - t) : t;
        float xv = 0.f;
        if (wave == 0) xv = X[(size_t)tx * (2 * G4) + dir * G4 + row];  // prefetch, used after reduce

        // spin on the data tags: thread stages h[tid] and h[tid+512]
        unsigned long long* pb = pd + (t & 1) * 1024;
        unsigned long long a, b;
        for (;;) {
            a = __hip_atomic_load(&pb[tid],       __ATOMIC_RELAXED, __HIP_MEMORY_SCOPE_AGENT);
            b = __hip_atomic_load(&pb[tid + 512], __ATOMIC_RELAXED, __HIP_MEMORY_SCOPE_AGENT);
            if (((unsigned)(a >> 32) == (unsigned)t) && ((unsigned)(b >> 32) == (unsigned)t)) break;
        }
        h_lds[tid]       = __uint_as_float((unsigned)a);
        h_lds[tid + 512] = __uint_as_float((unsigned)b);
        __syncthreads();

        // partial GEMV: this lane's row over its 128-col chunk (LDS broadcast reads)
        float a0 = 0.f, a1 = 0.f;
        const float4* h4 = (const float4*)(h_lds + coff);
#pragma unroll
        for (int i = 0; i < 32; i += 2) {
            float4 x = h4[i], y = h4[i + 1];
            a0 = fmaf(w[4 * i + 0], x.x, a0); a0 = fmaf(w[4 * i + 1], x.y, a0);
            a0 = fmaf(w[4 * i + 2], x.z, a0); a0 = fmaf(w[4 * i + 3], x.w, a0);
            a1 = fmaf(w[4 * i + 4], y.x, a1); a1 = fmaf(w[4 * i + 5], y.y, a1);
            a1 = fmaf(w[4 * i + 6], y.z, a1); a1 = fmaf(w[4 * i + 7], y.w, a1);
        }
        part[wave][lane] = a0 + a1;
        __syncthreads();

        if (wave == 0) {
            float g = xv;
#pragma unroll
            for (int wv = 0; wv < 8; ++wv) g += part[wv][lane];
            // gather the 4 gate pre-activations for hidden unit kk into lanes 0..15
            float g1 = __shfl(g, kk + 16);
            float g2 = __shfl(g, kk + 32);
            float g3 = __shfl(g, kk + 48);
            if (lane < 16) {
                float iv = sigm(g);
                float fv = sigm(g1);
                float gg = tanh_fast(g2);
                float ov = sigm(g3);
                float c = fv * c_reg + iv * gg;
                c_reg = c;
                float h = ov * tanh_fast(c);
                hs_out[(size_t)tx * 2048 + dir * HDIM + slice * 16 + lane] = h;
                unsigned long long pk = ((unsigned long long)(unsigned)(t + 1) << 32)
                                      | (unsigned long long)__float_as_uint(h);
                __hip_atomic_store(&pd[((t + 1) & 1) * 1024 + slice * 16 + lane], pk,
                                   __ATOMIC_RELAXED, __HIP_MEMORY_SCOPE_AGENT);
            }
        }
    }
}

// ---------------- feats = lstm_out @ W_tag^T + b_tag ----------------
__global__ __launch_bounds__(256) void feats_k(const float* __restrict__ hs,
                                               const float* __restrict__ Wtag,
                                               const float* __restrict__ btag,
                                               float* __restrict__ feats) {
    const int t = blockIdx.x;
    const int lane = threadIdx.x & 63, wave = threadIdx.x >> 6;
    const float* ht = hs + (size_t)t * 2048;
    for (int j = wave; j < KTAG; j += 4) {
        const float* wr = Wtag + (size_t)j * 2048;
        float acc = 0.f;
#pragma unroll
        for (int i = 0; i < 32; ++i) acc += wr[i * 64 + lane] * ht[i * 64 + lane];
#pragma unroll
        for (int off = 32; off; off >>= 1) acc += __shfl_xor(acc, off);
        if (lane == 0) feats[t * KTAG + j] = acc + btag[j];
    }
}

// ---------------- Viterbi (single wave, wave-synchronous, fv in registers) ----------------
__global__ __launch_bounds__(64) void viterbi_k(const float* __restrict__ feats,
                                                const float* __restrict__ trans,
                                                float* __restrict__ out) {
    __shared__ unsigned char bps[TT * KTAG];
    __shared__ short path[TT];
    const int j = threadIdx.x;
    const bool act = j < KTAG;
    float tr[KTAG];
    float tEnd = NEGV;
    float fvr = NEGV;
    if (act) {
#pragma unroll
        for (int p = 0; p < KTAG; ++p) tr[p] = trans[j * KTAG + p];
        tEnd = trans[END_TAG * KTAG + j];
        fvr = (j == START_TAG) ? 0.0f : NEGV;
    } else {
#pragma unroll
        for (int p = 0; p < KTAG; ++p) tr[p] = NEGV;
    }
    float ftn = act ? feats[j] : 0.f;
    for (int t = 0; t < TT; ++t) {
        float ft = ftn;
        if (t + 1 < TT) ftn = act ? feats[(t + 1) * KTAG + j] : 0.f;  // prefetch next step
        float m = -3.4e38f;
        int bp = 0;
#pragma unroll
        for (int p = 0; p < KTAG; ++p) {
            float fvp = __shfl(fvr, p);          // all 64 lanes participate
            float v = tr[p] + fvp;
            if (act && v > m) { m = v; bp = p; } // strict > keeps first max (argmax semantics)
        }
        fvr = m + ft;
        if (act) bps[t * KTAG + j] = (unsigned char)bp;
    }
    float term = act ? (fvr + tEnd) : -3.4e38f;
    float best = -3.4e38f;
    int bt = 0;
#pragma unroll
    for (int p = 0; p < KTAG; ++p) {
        float tv = __shfl(term, p);
        if (tv > best) { best = tv; bt = p; }
    }
    if (j == 0) {
        out[0] = best;
        int tag = bt;
        for (int t = TT - 1; t >= 0; --t) {
            path[t] = (short)tag;
            tag = bps[t * KTAG + tag];
        }
    }
    __syncthreads();
    for (int t = j; t < TT; t += 64) out[1 + t] = (float)path[t];
}

// ---------------- host ----------------
extern "C" void kernel_launch(void* const* d_in, const int* in_sizes, int n_in,
                              void* d_out, int out_size, void* d_ws, size_t ws_size,
                              hipStream_t stream) {
    const float* seq   = (const float*)d_in[0];
    const float* h0    = (const float*)d_in[1];
    const float* c0    = (const float*)d_in[2];
    const float* Wih_f = (const float*)d_in[3];
    const float* Whh_f = (const float*)d_in[4];
    const float* bih_f = (const float*)d_in[5];
    const float* bhh_f = (const float*)d_in[6];
    const float* Wih_r = (const float*)d_in[7];
    const float* Whh_r = (const float*)d_in[8];
    const float* bih_r = (const float*)d_in[9];
    const float* bhh_r = (const float*)d_in[10];
    const float* Wtag  = (const float*)d_in[11];
    const float* btag  = (const float*)d_in[12];
    const float* trans = (const float*)d_in[13];

    char* ws = (char*)d_ws;
    const size_t MB = 1ull << 20;
    __hip_bfloat16* seq_bf = (__hip_bfloat16*)(ws);              // 8 MB
    __hip_bfloat16* w_bf   = (__hip_bfloat16*)(ws + 8 * MB);     // 32 MB
    float* bias  = (float*)(ws + 40 * MB);                       // 32 KB
    float* X     = (float*)(ws + 41 * MB);                       // 64 MB
    float* hs    = (float*)(ws + 105 * MB);                      // 16 MB
    float* feats = (float*)(ws + 121 * MB);                      // 192 KB
    unsigned long long* pairs = (unsigned long long*)(ws + 122 * MB);  // 32 KB
    // ws poison 0xAA gives tag 0xAAAAAAAA != any t in [0, 2048] -> no stale match

    convert_bf16_k<<<256, 256, 0, stream>>>(seq, seq_bf, DD * TT);
    convert_bf16_k<<<512, 256, 0, stream>>>(Wih_f, w_bf, G4 * DD);
    convert_bf16_k<<<512, 256, 0, stream>>>(Wih_r, w_bf + (size_t)G4 * DD, G4 * DD);
    make_bias_k<<<32, 256, 0, stream>>>(bih_f, bhh_f, bih_r, bhh_r, bias);
    gemm_x_k<<<dim3(64, 16), 256, 0, stream>>>(seq_bf, w_bf, bias, X);

    {
        const float* a0 = Whh_f; const float* a1 = Whh_r;
        const float* a2 = h0;    const float* a3 = c0;
        const float* a4 = X;     unsigned long long* a5 = pairs;
        float* a6 = hs;
        void* args[] = {&a0, &a1, &a2, &a3, &a4, &a5, &a6};
        hipLaunchCooperativeKernel((const void*)lstm_recur_k, dim3(128), dim3(512), args, 0, stream);
    }

    feats_k<<<TT, 256, 0, stream>>>(hs, Wtag, btag, feats);
    viterbi_k<<<1, 64, 0, stream>>>(feats, trans, (float*)d_out);
}

// Round 5
// 5970.590 us; speedup vs baseline: 5.1366x; 1.0243x over previous
//
#include <hip/hip_runtime.h>
#include <hip/hip_bf16.h>
#include <stdint.h>

#define TT 2048
#define DD 2048
#define HDIM 1024
#define G4 4096
#define KTAG 22
#define END_TAG 20
#define START_TAG 21
#define NEGV (-10000.0f)

typedef __attribute__((ext_vector_type(8))) short bf16x8;
typedef __attribute__((ext_vector_type(4))) float f32x4;

__device__ __forceinline__ float sigm(float x) { return 1.0f / (1.0f + __expf(-x)); }
__device__ __forceinline__ float tanh_fast(float x) {
    float e = __expf(2.0f * x);
    return 1.0f - 2.0f / (e + 1.0f);
}
__device__ __forceinline__ unsigned bf16_bits(float f) {  // RNE
    unsigned x = __float_as_uint(f);
    return (x + 0x7FFFu + ((x >> 16) & 1u)) >> 16;
}

// ---------------- prep: fp32 -> bf16 ----------------
__global__ void convert_bf16_k(const float* __restrict__ src, __hip_bfloat16* __restrict__ dst, int n) {
    int i = blockIdx.x * blockDim.x + threadIdx.x;
    int stride = gridDim.x * blockDim.x;
    for (; i < n; i += stride) dst[i] = __float2bfloat16(src[i]);
}

__global__ void make_bias_k(const float* __restrict__ bih_f, const float* __restrict__ bhh_f,
                            const float* __restrict__ bih_r, const float* __restrict__ bhh_r,
                            float* __restrict__ ball) {
    int j = blockIdx.x * 256 + threadIdx.x;
    if (j < G4) ball[j] = bih_f[j] + bhh_f[j];
    else if (j < 2 * G4) ball[j] = bih_r[j - G4] + bhh_r[j - G4];
}

// ---------------- GEMM: X[t][j] = sum_k seq[t][k]*W[j][k] + bias[j] ----------------
#define LDT 40
__global__ __launch_bounds__(256) void gemm_x_k(const __hip_bfloat16* __restrict__ A,
                                                const __hip_bfloat16* __restrict__ B,
                                                const float* __restrict__ bias,
                                                float* __restrict__ X) {
    __shared__ unsigned short As[128 * LDT];
    __shared__ unsigned short Bs[128 * LDT];
    const int tid  = threadIdx.x;
    const int lane = tid & 63;
    const int wave = tid >> 6;
    const int wm = wave >> 1, wn = wave & 1;
    const int m0 = blockIdx.y * 128, n0 = blockIdx.x * 128;
    const int r15 = lane & 15, quad = lane >> 4;

    f32x4 acc[4][4];
#pragma unroll
    for (int i = 0; i < 4; ++i)
#pragma unroll
        for (int j = 0; j < 4; ++j) acc[i][j] = (f32x4){0.f, 0.f, 0.f, 0.f};

    for (int kt = 0; kt < DD; kt += 32) {
#pragma unroll
        for (int it = 0; it < 2; ++it) {
            int idx = it * 256 + tid;
            int row = idx >> 2, ch = idx & 3;
            uint4 va = *(const uint4*)(A + (size_t)(m0 + row) * DD + kt + ch * 8);
            *(uint4*)(&As[row * LDT + ch * 8]) = va;
            uint4 vb = *(const uint4*)(B + (size_t)(n0 + row) * DD + kt + ch * 8);
            *(uint4*)(&Bs[row * LDT + ch * 8]) = vb;
        }
        __syncthreads();
        bf16x8 af[4], bfr[4];
#pragma unroll
        for (int i = 0; i < 4; ++i)
            af[i] = *(const bf16x8*)(&As[(wm * 64 + i * 16 + r15) * LDT + quad * 8]);
#pragma unroll
        for (int j = 0; j < 4; ++j)
            bfr[j] = *(const bf16x8*)(&Bs[(wn * 64 + j * 16 + r15) * LDT + quad * 8]);
#pragma unroll
        for (int i = 0; i < 4; ++i)
#pragma unroll
            for (int j = 0; j < 4; ++j)
                acc[i][j] = __builtin_amdgcn_mfma_f32_16x16x32_bf16(af[i], bfr[j], acc[i][j], 0, 0, 0);
        __syncthreads();
    }
#pragma unroll
    for (int i = 0; i < 4; ++i) {
#pragma unroll
        for (int j = 0; j < 4; ++j) {
            int col = n0 + wn * 64 + j * 16 + r15;
            float b = bias[col];
#pragma unroll
            for (int r = 0; r < 4; ++r) {
                int row = m0 + wm * 64 + i * 16 + quad * 4 + r;
                X[(size_t)row * (2 * G4) + col] = acc[i][j][r] + b;
            }
        }
    }
}

// ---------------- persistent bidirectional LSTM recurrence ----------------
// grid = 128 WGs: dir = bid&1, slice = bid>>1. 512 threads (8 waves).
// Channel: pairs[dir][t&1][512] of 8B atoms, each = two (tag16|bf16) units.
// Thread tid polls exactly one atom; producer wave publishes one atom.
// Row-partitioned GEMV: wave owns 4 gates x 2 units; lane = (ri=lane>>3)*8+ch,
// ri = gate*2+u, ch covers 128 cols. 3x shfl_xor reduce, in-wave gates,
// per-wave immediate publish. One barrier/step; h_lds double-buffered by t&1.
__global__ __launch_bounds__(512, 2) void lstm_recur_k(
    const float* __restrict__ Whh_f, const float* __restrict__ Whh_r,
    const float* __restrict__ h0, const float* __restrict__ c0,
    const float* __restrict__ X,       // [2048][8192]
    unsigned long long* pairs,         // [2 dir][2 buf][512]
    float* __restrict__ hs_out)        // [2048][2048]
{
    const int bid = blockIdx.x;
    const int dir = bid & 1;
    const int slice = bid >> 1;
    const int tid = threadIdx.x;
    const int lane = tid & 63;
    const int wave = tid >> 6;

    __shared__ float h_lds[2][8 * 132];   // 132-float regions: conflict-free b128

    const float* Whh = dir ? Whh_r : Whh_f;
    unsigned long long* pd = pairs + (size_t)dir * 1024;

    const int ri = lane >> 3, ch = lane & 7;
    const int gamma = ri >> 1, u = ri & 1;
    const int unit = slice * 16 + wave * 2 + u;     // hidden unit of this lane's row
    const int row = gamma * HDIM + unit;            // Whh/X row, 0..4095

    // weights -> registers (one-time): this lane's row, cols [ch*128, ch*128+128)
    float w[128];
    {
        const float4* wp = (const float4*)(Whh + (size_t)row * HDIM + ch * 128);
#pragma unroll
        for (int i = 0; i < 32; ++i) {
            float4 v = wp[i];
            w[4 * i + 0] = v.x; w[4 * i + 1] = v.y; w[4 * i + 2] = v.z; w[4 * i + 3] = v.w;
        }
    }

    float c_reg = 0.f;
    if (ch == 0 && ri < 2) c_reg = c0[dir * HDIM + unit];

    // initial publish of h0 (tag 0) into buffer 0: one 8B atom per wave
    if (lane == 0) {
        float2 hv = *(const float2*)(h0 + dir * HDIM + slice * 16 + wave * 2);
        unsigned lo = bf16_bits(hv.x);          // tag 0 in hi16
        unsigned hi = bf16_bits(hv.y);
        __hip_atomic_store(&pd[slice * 8 + wave],
                           ((unsigned long long)hi << 32) | lo,
                           __ATOMIC_RELAXED, __HIP_MEMORY_SCOPE_AGENT);
    }

    const float* Xrow = X + dir * G4 + row;

    for (int t = 0; t < TT; ++t) {
        const int tx = dir ? (TT - 1 - t) : t;
        float xv = Xrow[(size_t)tx * (2 * G4)];    // issue early; consumed after reduce

        // poll own 8B atom (data IS the flag; both 16-bit tags must equal t)
        unsigned long long* pb = pd + (t & 1) * 512;
        const unsigned tg = (unsigned)t & 0xFFFFu;
        unsigned long long v;
        do {
            v = __hip_atomic_load(&pb[tid], __ATOMIC_RELAXED, __HIP_MEMORY_SCOPE_AGENT);
        } while ((((v >> 16) & 0xFFFFu) != tg) | ((unsigned)(v >> 48) != tg));

        // stage 2 units into the parity LDS buffer
        float* hl = h_lds[t & 1];
        float2 hw;
        hw.x = __uint_as_float((unsigned)(v & 0xFFFFu) << 16);
        hw.y = __uint_as_float((unsigned)((v >> 32) & 0xFFFFu) << 16);
        *(float2*)(hl + (tid >> 6) * 132 + ((2 * tid) & 127)) = hw;
        __syncthreads();

        // GEMV: lane's row over cols [ch*128, +128)
        const float4* h4 = (const float4*)(hl + ch * 132);
        float a0 = 0.f, a1 = 0.f;
#pragma unroll
        for (int i = 0; i < 32; i += 2) {
            float4 x = h4[i], y = h4[i + 1];
            a0 = fmaf(w[4 * i + 0], x.x, a0); a0 = fmaf(w[4 * i + 1], x.y, a0);
            a0 = fmaf(w[4 * i + 2], x.z, a0); a0 = fmaf(w[4 * i + 3], x.w, a0);
            a1 = fmaf(w[4 * i + 4], y.x, a1); a1 = fmaf(w[4 * i + 5], y.y, a1);
            a1 = fmaf(w[4 * i + 6], y.z, a1); a1 = fmaf(w[4 * i + 7], y.w, a1);
        }
        float g = a0 + a1;
        g += __shfl_xor(g, 1);
        g += __shfl_xor(g, 2);
        g += __shfl_xor(g, 4);   // all 8 ch-lanes of a row now hold the dot product
        g += xv;

        // gather the 4 gate rows of unit (ri&1): source ri = gate*2+u, lane = ri*8+ch
        float gI = __shfl(g, (0 + u) * 8 + ch);
        float gF = __shfl(g, (2 + u) * 8 + ch);
        float gG = __shfl(g, (4 + u) * 8 + ch);
        float gO = __shfl(g, (6 + u) * 8 + ch);
        float iv = sigm(gI), fv = sigm(gF), gg = tanh_fast(gG), ov = sigm(gO);
        float c = fv * c_reg + iv * gg;
        c_reg = c;                                   // valid on (ri<2, ch==0) lanes
        float h = ov * tanh_fast(c);
        float h1 = __shfl(h, 8);                     // unit u=1 value (lane 8)

        if (lane == 0) {
            *(float2*)(hs_out + (size_t)tx * 2048 + dir * HDIM + slice * 16 + wave * 2) =
                make_float2(h, h1);
            unsigned t1 = (unsigned)(t + 1) & 0xFFFFu;
            unsigned lo = (t1 << 16) | bf16_bits(h);
            unsigned hi = (t1 << 16) | bf16_bits(h1);
            __hip_atomic_store(&pd[((t + 1) & 1) * 512 + slice * 8 + wave],
                               ((unsigned long long)hi << 32) | lo,
                               __ATOMIC_RELAXED, __HIP_MEMORY_SCOPE_AGENT);
        }
    }
}

// ---------------- feats = lstm_out @ W_tag^T + b_tag ----------------
__global__ __launch_bounds__(256) void feats_k(const float* __restrict__ hs,
                                               const float* __restrict__ Wtag,
                                               const float* __restrict__ btag,
                                               float* __restrict__ feats) {
    const int t = blockIdx.x;
    const int lane = threadIdx.x & 63, wave = threadIdx.x >> 6;
    const float* ht = hs + (size_t)t * 2048;
    for (int j = wave; j < KTAG; j += 4) {
        const float* wr = Wtag + (size_t)j * 2048;
        float acc = 0.f;
#pragma unroll
        for (int i = 0; i < 32; ++i) acc += wr[i * 64 + lane] * ht[i * 64 + lane];
#pragma unroll
        for (int off = 32; off; off >>= 1) acc += __shfl_xor(acc, off);
        if (lane == 0) feats[t * KTAG + j] = acc + btag[j];
    }
}

// ---------------- Viterbi (single wave, wave-synchronous, 4-deep prefetch) ----------------
__global__ __launch_bounds__(64) void viterbi_k(const float* __restrict__ feats,
                                                const float* __restrict__ trans,
                                                float* __restrict__ out) {
    __shared__ unsigned char bps[TT * KTAG];
    __shared__ short path[TT];
    const int j = threadIdx.x;
    const bool act = j < KTAG;
    float tr[KTAG];
    float tEnd = NEGV;
    float fvr = NEGV;
    if (act) {
#pragma unroll
        for (int p = 0; p < KTAG; ++p) tr[p] = trans[j * KTAG + p];
        tEnd = trans[END_TAG * KTAG + j];
        fvr = (j == START_TAG) ? 0.0f : NEGV;
    } else {
#pragma unroll
        for (int p = 0; p < KTAG; ++p) tr[p] = NEGV;
    }
    float fbuf[4];
#pragma unroll
    for (int d = 0; d < 4; ++d) fbuf[d] = act ? feats[d * KTAG + j] : 0.f;
#pragma unroll 4
    for (int t = 0; t < TT; ++t) {
        float ft = fbuf[t & 3];
        if (t + 4 < TT) fbuf[t & 3] = act ? feats[(t + 4) * KTAG + j] : 0.f;  // deep prefetch
        float m = -3.4e38f;
        int bp = 0;
#pragma unroll
        for (int p = 0; p < KTAG; ++p) {
            float fvp = __shfl(fvr, p);          // all 64 lanes participate
            float v = tr[p] + fvp;
            if (act && v > m) { m = v; bp = p; }
        }
        fvr = m + ft;
        if (act) bps[t * KTAG + j] = (unsigned char)bp;
    }
    float term = act ? (fvr + tEnd) : -3.4e38f;
    float best = -3.4e38f;
    int bt = 0;
#pragma unroll
    for (int p = 0; p < KTAG; ++p) {
        float tv = __shfl(term, p);
        if (tv > best) { best = tv; bt = p; }
    }
    if (j == 0) {
        out[0] = best;
        int tag = bt;
        for (int t = TT - 1; t >= 0; --t) {
            path[t] = (short)tag;
            tag = bps[t * KTAG + tag];
        }
    }
    __syncthreads();
    for (int t = j; t < TT; t += 64) out[1 + t] = (float)path[t];
}

// ---------------- host ----------------
extern "C" void kernel_launch(void* const* d_in, const int* in_sizes, int n_in,
                              void* d_out, int out_size, void* d_ws, size_t ws_size,
                              hipStream_t stream) {
    const float* seq   = (const float*)d_in[0];
    const float* h0    = (const float*)d_in[1];
    const float* c0    = (const float*)d_in[2];
    const float* Wih_f = (const float*)d_in[3];
    const float* Whh_f = (const float*)d_in[4];
    const float* bih_f = (const float*)d_in[5];
    const float* bhh_f = (const float*)d_in[6];
    const float* Wih_r = (const float*)d_in[7];
    const float* Whh_r = (const float*)d_in[8];
    const float* bih_r = (const float*)d_in[9];
    const float* bhh_r = (const float*)d_in[10];
    const float* Wtag  = (const float*)d_in[11];
    const float* btag  = (const float*)d_in[12];
    const float* trans = (const float*)d_in[13];

    char* ws = (char*)d_ws;
    const size_t MB = 1ull << 20;
    __hip_bfloat16* seq_bf = (__hip_bfloat16*)(ws);              // 8 MB
    __hip_bfloat16* w_bf   = (__hip_bfloat16*)(ws + 8 * MB);     // 32 MB
    float* bias  = (float*)(ws + 40 * MB);                       // 32 KB
    float* X     = (float*)(ws + 41 * MB);                       // 64 MB
    float* hs    = (float*)(ws + 105 * MB);                      // 16 MB
    float* feats = (float*)(ws + 121 * MB);                      // 192 KB
    unsigned long long* pairs = (unsigned long long*)(ws + 122 * MB);  // 16 KB
    // ws poison 0xAA -> tag bits 0xAAAA, never equal to any t in [0, 2048]

    convert_bf16_k<<<256, 256, 0, stream>>>(seq, seq_bf, DD * TT);
    convert_bf16_k<<<512, 256, 0, stream>>>(Wih_f, w_bf, G4 * DD);
    convert_bf16_k<<<512, 256, 0, stream>>>(Wih_r, w_bf + (size_t)G4 * DD, G4 * DD);
    make_bias_k<<<32, 256, 0, stream>>>(bih_f, bhh_f, bih_r, bhh_r, bias);
    gemm_x_k<<<dim3(64, 16), 256, 0, stream>>>(seq_bf, w_bf, bias, X);

    {
        const float* a0 = Whh_f; const float* a1 = Whh_r;
        const float* a2 = h0;    const float* a3 = c0;
        const float* a4 = X;     unsigned long long* a5 = pairs;
        float* a6 = hs;
        void* args[] = {&a0, &a1, &a2, &a3, &a4, &a5, &a6};
        hipLaunchCooperativeKernel((const void*)lstm_recur_k, dim3(128), dim3(512), args, 0, stream);
    }

    feats_k<<<TT, 256, 0, stream>>>(hs, Wtag, btag, feats);
    viterbi_k<<<1, 64, 0, stream>>>(feats, trans, (float*)d_out);
}

// Round 7
// 4381.460 us; speedup vs baseline: 6.9996x; 1.3627x over previous
//
#include <hip/hip_runtime.h>
#include <hip/hip_bf16.h>
#include <stdint.h>

#define TT 2048
#define DD 2048
#define HDIM 1024
#define G4 4096
#define KTAG 22
#define END_TAG 20
#define START_TAG 21
#define NEGV (-10000.0f)
#define VNEG (-1e30f)
#define VC 64
#define VL 32

typedef __attribute__((ext_vector_type(8))) short bf16x8;
typedef __attribute__((ext_vector_type(4))) float f32x4;

__device__ __forceinline__ float sigm(float x) { return 1.0f / (1.0f + __expf(-x)); }
__device__ __forceinline__ float tanh_fast(float x) {
    float e = __expf(2.0f * x);
    return 1.0f - 2.0f / (e + 1.0f);
}
__device__ __forceinline__ unsigned bf16_bits(float f) {  // RNE
    unsigned x = __float_as_uint(f);
    return (x + 0x7FFFu + ((x >> 16) & 1u)) >> 16;
}

// ---------------- prep: fp32 -> bf16 ----------------
__global__ void convert_bf16_k(const float* __restrict__ src, __hip_bfloat16* __restrict__ dst, int n) {
    int i = blockIdx.x * blockDim.x + threadIdx.x;
    int stride = gridDim.x * blockDim.x;
    for (; i < n; i += stride) dst[i] = __float2bfloat16(src[i]);
}

__global__ void make_bias_k(const float* __restrict__ bih_f, const float* __restrict__ bhh_f,
                            const float* __restrict__ bih_r, const float* __restrict__ bhh_r,
                            float* __restrict__ ball) {
    int j = blockIdx.x * 256 + threadIdx.x;
    if (j < G4) ball[j] = bih_f[j] + bhh_f[j];
    else if (j < 2 * G4) ball[j] = bih_r[j - G4] + bhh_r[j - G4];
}

// ---------------- GEMM: X[t][j] = sum_k seq[t][k]*W[j][k] + bias[j] ----------------
#define LDT 40
__global__ __launch_bounds__(256) void gemm_x_k(const __hip_bfloat16* __restrict__ A,
                                                const __hip_bfloat16* __restrict__ B,
                                                const float* __restrict__ bias,
                                                float* __restrict__ X) {
    __shared__ unsigned short As[128 * LDT];
    __shared__ unsigned short Bs[128 * LDT];
    const int tid  = threadIdx.x;
    const int lane = tid & 63;
    const int wave = tid >> 6;
    const int wm = wave >> 1, wn = wave & 1;
    const int m0 = blockIdx.y * 128, n0 = blockIdx.x * 128;
    const int r15 = lane & 15, quad = lane >> 4;

    f32x4 acc[4][4];
#pragma unroll
    for (int i = 0; i < 4; ++i)
#pragma unroll
        for (int j = 0; j < 4; ++j) acc[i][j] = (f32x4){0.f, 0.f, 0.f, 0.f};

    for (int kt = 0; kt < DD; kt += 32) {
#pragma unroll
        for (int it = 0; it < 2; ++it) {
            int idx = it * 256 + tid;
            int row = idx >> 2, ch = idx & 3;
            uint4 va = *(const uint4*)(A + (size_t)(m0 + row) * DD + kt + ch * 8);
            *(uint4*)(&As[row * LDT + ch * 8]) = va;
            uint4 vb = *(const uint4*)(B + (size_t)(n0 + row) * DD + kt + ch * 8);
            *(uint4*)(&Bs[row * LDT + ch * 8]) = vb;
        }
        __syncthreads();
        bf16x8 af[4], bfr[4];
#pragma unroll
        for (int i = 0; i < 4; ++i)
            af[i] = *(const bf16x8*)(&As[(wm * 64 + i * 16 + r15) * LDT + quad * 8]);
#pragma unroll
        for (int j = 0; j < 4; ++j)
            bfr[j] = *(const bf16x8*)(&Bs[(wn * 64 + j * 16 + r15) * LDT + quad * 8]);
#pragma unroll
        for (int i = 0; i < 4; ++i)
#pragma unroll
            for (int j = 0; j < 4; ++j)
                acc[i][j] = __builtin_amdgcn_mfma_f32_16x16x32_bf16(af[i], bfr[j], acc[i][j], 0, 0, 0);
        __syncthreads();
    }
#pragma unroll
    for (int i = 0; i < 4; ++i) {
#pragma unroll
        for (int j = 0; j < 4; ++j) {
            int col = n0 + wn * 64 + j * 16 + r15;
            float b = bias[col];
#pragma unroll
            for (int r = 0; r < 4; ++r) {
                int row = m0 + wm * 64 + i * 16 + quad * 4 + r;
                X[(size_t)row * (2 * G4) + col] = acc[i][j][r] + b;
            }
        }
    }
}

// ---------------- persistent bidirectional LSTM recurrence ----------------
// ROUND-5 PROVEN TRANSPORT (agent-scope relaxed atomics, data-carries-tag).
// grid = 128 WGs: dir = bid&1, slice = bid>>1. 512 threads (8 waves).
// Channel: pairs[dir][t&1][512] of 8B atoms, each = two (tag16|bf16) units.
__global__ __launch_bounds__(512, 2) void lstm_recur_k(
    const float* __restrict__ Whh_f, const float* __restrict__ Whh_r,
    const float* __restrict__ h0, const float* __restrict__ c0,
    const float* __restrict__ X,       // [2048][8192]
    unsigned long long* pairs,         // [2 dir][2 buf][512]
    float* __restrict__ hs_out)        // [2048][2048]
{
    const int bid = blockIdx.x;
    const int dir = bid & 1;
    const int slice = bid >> 1;
    const int tid = threadIdx.x;
    const int lane = tid & 63;
    const int wave = tid >> 6;

    __shared__ float h_lds[2][8 * 132];   // 132-float regions: conflict-free b128

    const float* Whh = dir ? Whh_r : Whh_f;
    unsigned long long* pd = pairs + (size_t)dir * 1024;

    const int ri = lane >> 3, ch = lane & 7;
    const int u = ri & 1;
    const int unit = slice * 16 + wave * 2 + u;     // hidden unit of this lane's row
    const int row = (ri >> 1) * HDIM + unit;        // Whh/X row, 0..4095

    // weights -> registers (one-time): this lane's row, cols [ch*128, ch*128+128)
    float w[128];
    {
        const float4* wp = (const float4*)(Whh + (size_t)row * HDIM + ch * 128);
#pragma unroll
        for (int i = 0; i < 32; ++i) {
            float4 v = wp[i];
            w[4 * i + 0] = v.x; w[4 * i + 1] = v.y; w[4 * i + 2] = v.z; w[4 * i + 3] = v.w;
        }
    }

    float c_reg = 0.f;
    if (ch == 0 && ri < 2) c_reg = c0[dir * HDIM + unit];

    // initial publish of h0 (tag 0) into buffer 0: one 8B atom per wave
    if (lane == 0) {
        float2 hv = *(const float2*)(h0 + dir * HDIM + slice * 16 + wave * 2);
        unsigned lo = bf16_bits(hv.x);          // tag 0 in hi16
        unsigned hi = bf16_bits(hv.y);
        __hip_atomic_store(&pd[slice * 8 + wave],
                           ((unsigned long long)hi << 32) | lo,
                           __ATOMIC_RELAXED, __HIP_MEMORY_SCOPE_AGENT);
    }

    const float* Xrow = X + dir * G4 + row;

    for (int t = 0; t < TT; ++t) {
        const int tx = dir ? (TT - 1 - t) : t;
        float xv = Xrow[(size_t)tx * (2 * G4)];    // issued before poll: hides under spin

        // poll own 8B atom (data IS the flag; both 16-bit tags must equal t)
        unsigned long long* pb = pd + (t & 1) * 512;
        const unsigned tg = (unsigned)t & 0xFFFFu;
        unsigned long long v;
        do {
            v = __hip_atomic_load(&pb[tid], __ATOMIC_RELAXED, __HIP_MEMORY_SCOPE_AGENT);
        } while ((((v >> 16) & 0xFFFFu) != tg) | ((unsigned)(v >> 48) != tg));

        // stage 2 units (unit index = 2*tid) into the parity LDS buffer
        float* hl = h_lds[t & 1];
        float2 hw;
        hw.x = __uint_as_float((unsigned)(v & 0xFFFFu) << 16);
        hw.y = __uint_as_float((unsigned)((v >> 32) & 0xFFFFu) << 16);
        *(float2*)(hl + (tid >> 6) * 132 + ((2 * tid) & 127)) = hw;
        __syncthreads();

        // GEMV: lane's row over cols [ch*128, +128)
        const float4* h4 = (const float4*)(hl + ch * 132);
        float a0 = 0.f, a1 = 0.f;
#pragma unroll
        for (int i = 0; i < 32; i += 2) {
            float4 x = h4[i], y = h4[i + 1];
            a0 = fmaf(w[4 * i + 0], x.x, a0); a0 = fmaf(w[4 * i + 1], x.y, a0);
            a0 = fmaf(w[4 * i + 2], x.z, a0); a0 = fmaf(w[4 * i + 3], x.w, a0);
            a1 = fmaf(w[4 * i + 4], y.x, a1); a1 = fmaf(w[4 * i + 5], y.y, a1);
            a1 = fmaf(w[4 * i + 6], y.z, a1); a1 = fmaf(w[4 * i + 7], y.w, a1);
        }
        float g = a0 + a1;
        g += __shfl_xor(g, 1);
        g += __shfl_xor(g, 2);
        g += __shfl_xor(g, 4);   // all 8 ch-lanes of a row now hold the dot product
        g += xv;

        // gather the 4 gate rows of unit u: source ri = gate*2+u, lane = ri*8+ch
        float gI = __shfl(g, (0 + u) * 8 + ch);
        float gF = __shfl(g, (2 + u) * 8 + ch);
        float gG = __shfl(g, (4 + u) * 8 + ch);
        float gO = __shfl(g, (6 + u) * 8 + ch);
        float iv = sigm(gI), fv = sigm(gF), gg = tanh_fast(gG), ov = sigm(gO);
        float c = fv * c_reg + iv * gg;
        c_reg = c;                                   // valid on (ri<2, ch==0) lanes
        float h = ov * tanh_fast(c);
        float h1 = __shfl(h, 8);                     // unit u=1 value (lane 8)

        if (lane == 0) {
            *(float2*)(hs_out + (size_t)tx * 2048 + dir * HDIM + slice * 16 + wave * 2) =
                make_float2(h, h1);
            unsigned t1 = (unsigned)(t + 1) & 0xFFFFu;
            unsigned lo = (t1 << 16) | bf16_bits(h);
            unsigned hi = (t1 << 16) | bf16_bits(h1);
            __hip_atomic_store(&pd[((t + 1) & 1) * 512 + slice * 8 + wave],
                               ((unsigned long long)hi << 32) | lo,
                               __ATOMIC_RELAXED, __HIP_MEMORY_SCOPE_AGENT);
        }
    }
}

// ---------------- feats = lstm_out @ W_tag^T + b_tag ----------------
__global__ __launch_bounds__(256) void feats_k(const float* __restrict__ hs,
                                               const float* __restrict__ Wtag,
                                               const float* __restrict__ btag,
                                               float* __restrict__ feats) {
    const int t = blockIdx.x;
    const int lane = threadIdx.x & 63, wave = threadIdx.x >> 6;
    const float* ht = hs + (size_t)t * 2048;
    for (int j = wave; j < KTAG; j += 4) {
        const float* wr = Wtag + (size_t)j * 2048;
        float acc = 0.f;
#pragma unroll
        for (int i = 0; i < 32; ++i) acc += wr[i * 64 + lane] * ht[i * 64 + lane];
#pragma unroll
        for (int off = 32; off; off >>= 1) acc += __shfl_xor(acc, off);
        if (lane == 0) feats[t * KTAG + j] = acc + btag[j];
    }
}

// ---------------- blocked Viterbi: K1 per-chunk (max,+) composition ----------------
__global__ __launch_bounds__(512) void vit_compose_k(const float* __restrict__ feats,
                                                     const float* __restrict__ trans,
                                                     float* __restrict__ Cmat) { // [VC][n][j]
    __shared__ float c_lds[KTAG * KTAG];
    __shared__ float ft_s[KTAG];
    const int tid = threadIdx.x;
    const int chunk = blockIdx.x;
    const int j = tid / KTAG, n = tid % KTAG;
    const bool act = (tid < KTAG * KTAG);
    float tr_n[KTAG];
    if (act)
#pragma unroll
        for (int p = 0; p < KTAG; ++p) tr_n[p] = trans[n * KTAG + p];
    float c = (act && n == j) ? 0.f : VNEG;
    for (int s = 0; s < VL; ++s) {
        if (act) c_lds[j * KTAG + n] = c;
        if (tid < KTAG) ft_s[tid] = feats[(chunk * VL + s) * KTAG + tid];
        __syncthreads();
        if (act) {
            float m = VNEG;
#pragma unroll
            for (int p = 0; p < KTAG; ++p)
                m = fmaxf(m, tr_n[p] + c_lds[j * KTAG + p]);
            c = m + ft_s[n];
        }
        __syncthreads();
    }
    if (act) Cmat[chunk * KTAG * KTAG + n * KTAG + j] = c;
}

// K2: serial scan over chunk compositions (single wave)
__global__ __launch_bounds__(64) void vit_scan_k(const float* __restrict__ Cmat,
                                                 const float* __restrict__ trans,
                                                 float* __restrict__ fv_start,  // [VC][22]
                                                 float* __restrict__ scan_out)  // [0]=score [1]=best tag
{
    const int n = threadIdx.x;
    const bool act = n < KTAG;
    float fv = (act && n == START_TAG) ? 0.f : NEGV;
    for (int i = 0; i < VC; ++i) {
        if (act) fv_start[i * KTAG + n] = fv;
        float Crow[KTAG];
        if (act)
#pragma unroll
            for (int p = 0; p < KTAG; ++p) Crow[p] = Cmat[i * KTAG * KTAG + n * KTAG + p];
        float m = VNEG;
#pragma unroll
        for (int p = 0; p < KTAG; ++p) {
            float fvp = __shfl(fv, p);
            if (act) m = fmaxf(m, Crow[p] + fvp);
        }
        fv = m;
    }
    float term = act ? (fv + trans[END_TAG * KTAG + n]) : VNEG;
    float best = VNEG; int bt = 0;
#pragma unroll
    for (int p = 0; p < KTAG; ++p) {
        float tv = __shfl(term, p);
        if (tv > best) { best = tv; bt = p; }
    }
    if (n == 0) { scan_out[0] = best; scan_out[1] = (float)bt; }
}

// K3: per-chunk detailed DP from fv_start, store backpointers + entry ancestors
__global__ __launch_bounds__(64) void vit_detail_k(const float* __restrict__ feats,
                                                   const float* __restrict__ trans,
                                                   const float* __restrict__ fv_start,
                                                   unsigned char* __restrict__ bps,   // [TT][22]
                                                   unsigned char* __restrict__ anc)   // [VC][22]
{
    const int i = blockIdx.x;
    const int n = threadIdx.x;
    const bool act = n < KTAG;
    float tr_n[KTAG];
    if (act)
#pragma unroll
        for (int p = 0; p < KTAG; ++p) tr_n[p] = trans[n * KTAG + p];
    float fv = act ? fv_start[i * KTAG + n] : VNEG;
    int an = n;
    for (int s = 0; s < VL; ++s) {
        int t = i * VL + s;
        float ft = act ? feats[t * KTAG + n] : 0.f;
        float m = VNEG; int bp = 0;
#pragma unroll
        for (int p = 0; p < KTAG; ++p) {
            float fvp = __shfl(fv, p);
            float vv = tr_n[p] + fvp;
            if (act && vv > m) { m = vv; bp = p; }
        }
        fv = m + ft;
        int anew = __shfl(an, bp);
        if (act) {
            an = anew;
            bps[t * KTAG + n] = (unsigned char)bp;
        }
    }
    if (act) anc[i * KTAG + n] = (unsigned char)an;
}

// K4: chunk-boundary chain + parallel per-chunk backtrack (all in LDS)
__global__ __launch_bounds__(256) void vit_backtrack_k(const unsigned char* __restrict__ bps,
                                                       const unsigned char* __restrict__ anc,
                                                       const float* __restrict__ scan_out,
                                                       float* __restrict__ out)
{
    __shared__ unsigned char bps_s[TT * KTAG];
    __shared__ unsigned char anc_s[VC * KTAG];
    __shared__ unsigned char chunk_exit[VC];
    __shared__ short path[TT];
    const int tid = threadIdx.x;
    for (int idx = tid * 16; idx < TT * KTAG; idx += 256 * 16)
        *(int4*)(bps_s + idx) = *(const int4*)(bps + idx);
    for (int idx = tid; idx < VC * KTAG; idx += 256) anc_s[idx] = anc[idx];
    __syncthreads();
    if (tid == 0) {
        int tag = (int)scan_out[1];
        for (int i = VC - 1; i >= 0; --i) {
            chunk_exit[i] = (unsigned char)tag;
            tag = anc_s[i * KTAG + tag];
        }
        out[0] = scan_out[0];
    }
    __syncthreads();
    if (tid < VC) {
        int tag = chunk_exit[tid];
        for (int s = VL - 1; s >= 0; --s) {
            int t = tid * VL + s;
            path[t] = (short)tag;
            tag = bps_s[t * KTAG + tag];
        }
    }
    __syncthreads();
    for (int t = tid; t < TT; t += 256) out[1 + t] = (float)path[t];
}

// ---------------- host ----------------
extern "C" void kernel_launch(void* const* d_in, const int* in_sizes, int n_in,
                              void* d_out, int out_size, void* d_ws, size_t ws_size,
                              hipStream_t stream) {
    const float* seq   = (const float*)d_in[0];
    const float* h0    = (const float*)d_in[1];
    const float* c0    = (const float*)d_in[2];
    const float* Wih_f = (const float*)d_in[3];
    const float* Whh_f = (const float*)d_in[4];
    const float* bih_f = (const float*)d_in[5];
    const float* bhh_f = (const float*)d_in[6];
    const float* Wih_r = (const float*)d_in[7];
    const float* Whh_r = (const float*)d_in[8];
    const float* bih_r = (const float*)d_in[9];
    const float* bhh_r = (const float*)d_in[10];
    const float* Wtag  = (const float*)d_in[11];
    const float* btag  = (const float*)d_in[12];
    const float* trans = (const float*)d_in[13];

    char* ws = (char*)d_ws;
    const size_t MB = 1ull << 20;
    const size_t KB = 1ull << 10;
    __hip_bfloat16* seq_bf = (__hip_bfloat16*)(ws);              // 8 MB
    __hip_bfloat16* w_bf   = (__hip_bfloat16*)(ws + 8 * MB);     // 32 MB
    float* bias  = (float*)(ws + 40 * MB);                       // 32 KB
    float* X     = (float*)(ws + 41 * MB);                       // 64 MB
    float* hs    = (float*)(ws + 105 * MB);                      // 16 MB
    float* feats = (float*)(ws + 121 * MB);                      // 180 KB
    unsigned long long* pairs = (unsigned long long*)(ws + 122 * MB);   // 16 KB
    float* Cmat     = (float*)(ws + 122 * MB + 128 * KB);        // 121 KB
    float* fv_start = (float*)(ws + 122 * MB + 256 * KB);        // 5.6 KB
    float* scan_out = (float*)(ws + 122 * MB + 272 * KB);        // 8 B
    unsigned char* bps = (unsigned char*)(ws + 122 * MB + 288 * KB);    // 45 KB
    unsigned char* anc = (unsigned char*)(ws + 122 * MB + 352 * KB);    // 1.4 KB
    // ws poison 0xAA -> channel tag bits 0xAAAA, never equal to any t in [0, 2048]

    convert_bf16_k<<<1024, 256, 0, stream>>>(seq, seq_bf, DD * TT);
    convert_bf16_k<<<1024, 256, 0, stream>>>(Wih_f, w_bf, G4 * DD);
    convert_bf16_k<<<1024, 256, 0, stream>>>(Wih_r, w_bf + (size_t)G4 * DD, G4 * DD);
    make_bias_k<<<32, 256, 0, stream>>>(bih_f, bhh_f, bih_r, bhh_r, bias);
    gemm_x_k<<<dim3(64, 16), 256, 0, stream>>>(seq_bf, w_bf, bias, X);

    {
        const float* a0 = Whh_f; const float* a1 = Whh_r;
        const float* a2 = h0;    const float* a3 = c0;
        const float* a4 = X;     unsigned long long* a5 = pairs;
        float* a6 = hs;
        void* args[] = {&a0, &a1, &a2, &a3, &a4, &a5, &a6};
        hipLaunchCooperativeKernel((const void*)lstm_recur_k, dim3(128), dim3(512), args, 0, stream);
    }

    feats_k<<<TT, 256, 0, stream>>>(hs, Wtag, btag, feats);
    vit_compose_k<<<VC, 512, 0, stream>>>(feats, trans, Cmat);
    vit_scan_k<<<1, 64, 0, stream>>>(Cmat, trans, fv_start, scan_out);
    vit_detail_k<<<VC, 64, 0, stream>>>(feats, trans, fv_start, bps, anc);
    vit_backtrack_k<<<1, 256, 0, stream>>>(bps, anc, scan_out, (float*)d_out);
}